// Round 3
// baseline (12548.567 us; speedup 1.0000x reference)
//
#include <hip/hip_runtime.h>
#include <math.h>

typedef __attribute__((ext_vector_type(8))) short short8;
typedef __attribute__((ext_vector_type(4))) float f32x4;
typedef unsigned short ushort_t;
typedef unsigned int uint32;
typedef unsigned long long u64;

// ---------------- ws layout (float units) ----------------
#define WS_E      0        // e[4096]
#define WS_SCORES 4096     // scores[4096]
#define WS_ATT    8192     // att[4096]
#define WS_HID    12288    // hid[1024]

// ---------------- d_out layout (float units from base) ----------------
#define ENERGY_OFF   1024
#define XP_OFF       0          // bf16 xp[2][4096][1536]
#define OUTPUTS_OFF  6291456    // float outputs[4096][1024]
#define XBF_OFF      10485760   // bf16 x[4096][512]
#define WIH_OFF      11534336   // bf16 w_ih[3072][512]
#define WHH_OFF      12320768   // bf16 w_hh[2][1536][512]  (ends 13107200)
// h exchange buffers inside energy region. Offsets chosen so k_energy's diag
// element for the covering rows (3200, 3201) falls OUTSIDE these column spans.
#define HBF_OFF      13107200   // u64 fast[2 dir][2 par][256]  (row 3200, cols<2048)
#define HBS_OFF      13111296   // u64 slow[2 dir][2 par][256]  (row 3201, cols<2048)

__device__ __forceinline__ ushort_t f2bf(float f) {
  uint32 x = __float_as_uint(f);
  return (ushort_t)((x + 0x7fffu + ((x >> 16) & 1u)) >> 16);
}
__device__ __forceinline__ float bf2f(ushort_t u) {
  return __uint_as_float(((uint32)u) << 16);
}
// L1-bypassing load that hits the XCD L2 (fast path; same-XCD coherent only).
__device__ __forceinline__ u64 load_u64_sc0(const u64* p) {
  u64 r;
  asm volatile("global_load_dwordx2 %0, %1, off sc0\n\ts_waitcnt vmcnt(0)"
               : "=v"(r) : "v"(p) : "memory");
  return r;
}
__device__ __forceinline__ void store_u64_l2(u64* p, u64 v) {
  asm volatile("global_store_dwordx2 %0, %1, off" :: "v"(p), "v"(v) : "memory");
}

// ============ K1: e[t], x_bf, weight bf16 conversion ============
__global__ __launch_bounds__(256) void k_prep(
    const float* __restrict__ query, const float* __restrict__ input,
    const float* __restrict__ fc_w, const float* __restrict__ fc_b,
    const float* __restrict__ w_ih_f, const float* __restrict__ w_ih_b,
    const float* __restrict__ w_hh_f, const float* __restrict__ w_hh_b,
    float* __restrict__ ws, float* __restrict__ outbase)
{
  int bid = blockIdx.x, tid = threadIdx.x;
  ushort_t* xbf   = (ushort_t*)(outbase + ENERGY_OFF + XBF_OFF);
  ushort_t* wihbf = (ushort_t*)(outbase + ENERGY_OFF + WIH_OFF);
  ushort_t* whhbf = (ushort_t*)(outbase + ENERGY_OFF + WHH_OFF);

  if (bid < 512) {
    int lane = tid & 63, wv = tid >> 6;
    float bconst = fc_b[0];
    const float4* w4 = (const float4*)fc_w;
    float4 b0 = w4[lane*2], b1 = w4[lane*2+1];
    for (int it = 0; it < 2; ++it) {
      int t = bid*8 + it*4 + wv;
      const float4* q4 = (const float4*)(query + (size_t)t*512);
      float4 a0 = q4[lane*2], a1 = q4[lane*2+1];
      float p = a0.x*b0.x + a0.y*b0.y + a0.z*b0.z + a0.w*b0.w
              + a1.x*b1.x + a1.y*b1.y + a1.z*b1.z + a1.w*b1.w;
      #pragma unroll
      for (int m = 1; m < 64; m <<= 1) p += __shfl_xor(p, m, 64);
      float e = p + bconst;
      if (lane == 0) ws[WS_E + t] = e;
      const float4* in4 = (const float4*)(input + (size_t)t*512);
      float4 x0 = in4[lane*2], x1 = in4[lane*2+1];
      short8 o;
      o[0]=(short)f2bf(e*x0.x); o[1]=(short)f2bf(e*x0.y);
      o[2]=(short)f2bf(e*x0.z); o[3]=(short)f2bf(e*x0.w);
      o[4]=(short)f2bf(e*x1.x); o[5]=(short)f2bf(e*x1.y);
      o[6]=(short)f2bf(e*x1.z); o[7]=(short)f2bf(e*x1.w);
      *(short8*)(xbf + (size_t)t*512 + lane*8) = o;
    }
  } else {
    size_t gid = (size_t)(bid - 512)*2048 + (size_t)tid*8;
    const float* src; ushort_t* dst; size_t doff, soff;
    if (gid < 786432)        { src = w_ih_f; dst = wihbf; doff = gid;          soff = gid; }
    else if (gid < 1572864)  { src = w_ih_b; dst = wihbf; doff = gid;          soff = gid - 786432; }
    else if (gid < 2359296)  { src = w_hh_f; dst = whhbf; doff = gid - 1572864; soff = gid - 1572864; }
    else                     { src = w_hh_b; dst = whhbf; doff = gid - 1572864; soff = gid - 2359296; }
    float4 v0 = *(const float4*)(src + soff);
    float4 v1 = *(const float4*)(src + soff + 4);
    short8 o;
    o[0]=(short)f2bf(v0.x); o[1]=(short)f2bf(v0.y); o[2]=(short)f2bf(v0.z); o[3]=(short)f2bf(v0.w);
    o[4]=(short)f2bf(v1.x); o[5]=(short)f2bf(v1.y); o[6]=(short)f2bf(v1.z); o[7]=(short)f2bf(v1.w);
    *(short8*)(dst + doff) = o;
  }
}

// ============ K2: xp GEMM  M=4096(t) x N=3072(j stacked f,b) x K=512 ============
__global__ __launch_bounds__(256) void k_xp_gemm(
    const float* __restrict__ b_ih_f, const float* __restrict__ b_ih_b,
    float* __restrict__ outbase)
{
  const ushort_t* xbf   = (const ushort_t*)(outbase + ENERGY_OFF + XBF_OFF);
  const ushort_t* wihbf = (const ushort_t*)(outbase + ENERGY_OFF + WIH_OFF);
  ushort_t* xpbf = (ushort_t*)(outbase + ENERGY_OFF + XP_OFF);

  int m0 = blockIdx.x * 64, n0 = blockIdx.y * 64;
  bool rev = (n0 >= 1536);
  __shared__ ushort_t As[64*40];
  __shared__ ushort_t Bs[64*40];
  int tid = threadIdx.x;
  int lane = tid & 63, wv = tid >> 6, l15 = lane & 15, quad = lane >> 4;
  int mw = (wv & 1)*32, nw = (wv >> 1)*32;
  f32x4 acc[2][2] = {};
  int lr = tid >> 2, lc = (tid & 3)*8;
  int t_eff = rev ? (4095 - (m0 + lr)) : (m0 + lr);
  const short8* asrc = (const short8*)(xbf + (size_t)t_eff*512 + lc);
  const short8* bsrc = (const short8*)(wihbf + (size_t)(n0 + lr)*512 + lc);

  for (int ks = 0; ks < 16; ++ks) {
    short8 av = asrc[ks*4];
    short8 bv = bsrc[ks*4];
    __syncthreads();
    *(short8*)(As + lr*40 + lc) = av;
    *(short8*)(Bs + lr*40 + lc) = bv;
    __syncthreads();
    short8 bf0 = *(const short8*)(Bs + (nw + l15)*40 + quad*8);
    short8 bf1 = *(const short8*)(Bs + (nw + 16 + l15)*40 + quad*8);
    #pragma unroll
    for (int mi = 0; mi < 2; ++mi) {
      short8 af = *(const short8*)(As + (mw + mi*16 + l15)*40 + quad*8);
      acc[mi][0] = __builtin_amdgcn_mfma_f32_16x16x32_bf16(af, bf0, acc[mi][0], 0, 0, 0);
      acc[mi][1] = __builtin_amdgcn_mfma_f32_16x16x32_bf16(af, bf1, acc[mi][1], 0, 0, 0);
    }
  }
  #pragma unroll
  for (int mi = 0; mi < 2; ++mi) {
    #pragma unroll
    for (int ni = 0; ni < 2; ++ni) {
      int j = n0 + nw + ni*16 + l15;
      int d2 = (j >= 1536) ? 1 : 0;
      int jj = j - d2*1536;
      float bias = d2 ? b_ih_b[jj] : b_ih_f[jj];
      int trow_base = m0 + mw + mi*16 + quad*4;
      #pragma unroll
      for (int r = 0; r < 4; ++r) {
        xpbf[((size_t)(d2*4096 + trow_base + r))*1536 + jj] = f2bf(acc[mi][ni][r] + bias);
      }
    }
  }
}

// ============ K3: persistent bidirectional GRU scan ============
// Active blocks: blk%8==0 -> fwd, blk%8==1 -> bwd (each direction lands on ONE
// XCD if blockIdx%8 round-robin holds). 8 WGs/dir, 64 ch each, 320 threads:
//   waves 0..3: poll + MFMA (W_hh VGPR-resident) + gates + FAST publish
//   wave 4: xp streaming + slow (MALL) re-publish + outputs stores (off-path)
// Fast path: plain store -> sc0 load meeting in the shared XCD L2 (~200cy RT).
// Slow path (correct under ANY placement): agent-scope buffer, self-validating
// tags (tag = t+1; never matches zeroed or 0xAA-poisoned memory).
__global__ __launch_bounds__(320, 1) void k_gru(
    const float* __restrict__ b_hh_f, const float* __restrict__ b_hh_b,
    float* __restrict__ ws, float* __restrict__ outbase)
{
  int blk = blockIdx.x;
  int sel = blk & 7;
  if (sel >= 2) return;
  int d = sel;
  int g = blk >> 3;

  const ushort_t* xpbf  = (const ushort_t*)(outbase + ENERGY_OFF + XP_OFF);
  const ushort_t* whhbf = (const ushort_t*)(outbase + ENERGY_OFF + WHH_OFF);
  float* outputs = outbase + ENERGY_OFF + OUTPUTS_OFF;
  u64* hbF = ((u64*)(outbase + ENERGY_OFF + HBF_OFF)) + d*512;
  u64* hbS = ((u64*)(outbase + ENERGY_OFF + HBS_OFF)) + d*512;

  int tid = threadIdx.x;
  int lane = tid & 63, wv = tid >> 6, l15 = lane & 15, quad = lane >> 4;
  int I0 = g * 64;
  int cbase = wv*16 + quad*4;      // meaningful for wv<4
  int C0 = I0 + cbase;

  __shared__ ushort_t h_bf[2][512];
  __shared__ ushort_t xpq[2][192];

  const ushort_t* xpd = xpbf + (size_t)d*4096*1536;

  short8 wfrag[3][16];
  float bhv[12];
  float hprev[4] = {0.f, 0.f, 0.f, 0.f};
  bool use_fast = true;

  if (wv < 4) {
    const ushort_t* wbase = whhbf + (size_t)d*1536*512;
    const float* bhh = d ? b_hh_b : b_hh_f;
    #pragma unroll
    for (int g3 = 0; g3 < 3; ++g3) {
      const ushort_t* wrow = wbase + ((size_t)(g3*512 + I0 + wv*16 + l15))*512 + quad*8;
      #pragma unroll
      for (int kc = 0; kc < 16; ++kc)
        wfrag[g3][kc] = *(const short8*)(wrow + kc*32);
      float4 b4 = *(const float4*)(bhh + g3*512 + C0);
      bhv[g3*4+0] = b4.x; bhv[g3*4+1] = b4.y; bhv[g3*4+2] = b4.z; bhv[g3*4+3] = b4.w;
    }
    ((uint32*)h_bf)[tid] = 0;
    ((uint32*)h_bf)[tid + 256] = 0;
  }
  int xi = lane;
  u64 xreg = 0;
  if (wv == 4 && xi < 48) {
    xreg = *(const u64*)(xpd + ((size_t)(xi >> 4)*512 + I0 + (xi & 15)*4));
  }

  for (int t = 0; t < 4096; ++t) {
    int par = t & 1;
    if (wv < 4) {
      // ---- poll foreign channel pairs (one u64 per thread) ----
      if (t > 0 && (tid >> 5) != g) {
        uint32 want = (uint32)t & 0xffffu;          // tag of h(t-1) is (t-1)+1
        const u64* aF = hbF + par*256 + tid;
        u64 v = 0; bool ok = false;
        if (use_fast) {
          int tries = (t == 1) ? 64 : 8;
          for (int k = 0; k < tries; ++k) {
            v = load_u64_sc0(aF);
            if (((uint32)v & 0xffffu) == want &&
                (((uint32)(v >> 32)) & 0xffffu) == want) { ok = true; break; }
          }
          if (t == 1 && !ok) use_fast = false;      // sticky: placement adverse
        }
        while (!ok) {
          v = __hip_atomic_load(hbS + par*256 + tid, __ATOMIC_RELAXED,
                                __HIP_MEMORY_SCOPE_AGENT);
          ok = (((uint32)v & 0xffffu) == want) &&
               ((((uint32)(v >> 32)) & 0xffffu) == want);
          if (!ok) __builtin_amdgcn_s_sleep(2);
        }
        ((uint32*)h_bf[par])[tid] =
            (uint32)(((v >> 16) & 0xffffu) | ((v >> 32) & 0xffff0000u));
      }
    } else {
      // ---- loader wave: xp commit + deferred slow/outputs publish of h(t-1) ----
      if (xi < 48) *(u64*)(&xpq[par][xi*4]) = xreg;
      if (t > 0 && lane < 32) {
        uint32 want = (uint32)t & 0xffffu;
        const u64* aF = hbF + par*256 + g*32 + lane; // own WG words: same-CU, always fast
        u64 v;
        for (;;) {
          v = load_u64_sc0(aF);
          if (((uint32)v & 0xffffu) == want &&
              (((uint32)(v >> 32)) & 0xffffu) == want) break;
        }
        __hip_atomic_store(hbS + par*256 + g*32 + lane, v, __ATOMIC_RELAXED,
                           __HIP_MEMORY_SCOPE_AGENT);
        int row = d ? (4095 - (t - 1)) : (t - 1);
        float2 o;
        o.x = bf2f((ushort_t)(v >> 16));
        o.y = bf2f((ushort_t)(v >> 48));
        *(float2*)(outputs + (size_t)row*1024 + d*512 + I0 + lane*2) = o;
      }
    }
    __syncthreads();
    if (wv < 4) {
      // ---- matvec: 6 independent chains of 8 dependent MFMAs ----
      f32x4 ar0 = {0.f,0.f,0.f,0.f}, ar1 = {0.f,0.f,0.f,0.f};
      f32x4 az0 = {0.f,0.f,0.f,0.f}, az1 = {0.f,0.f,0.f,0.f};
      f32x4 an0 = {0.f,0.f,0.f,0.f}, an1 = {0.f,0.f,0.f,0.f};
      #pragma unroll
      for (int kc = 0; kc < 8; ++kc) {
        short8 hv0 = *(const short8*)(&h_bf[par][kc*32 + quad*8]);
        short8 hv1 = *(const short8*)(&h_bf[par][(kc + 8)*32 + quad*8]);
        ar0 = __builtin_amdgcn_mfma_f32_16x16x32_bf16(wfrag[0][kc],     hv0, ar0, 0, 0, 0);
        ar1 = __builtin_amdgcn_mfma_f32_16x16x32_bf16(wfrag[0][kc + 8], hv1, ar1, 0, 0, 0);
        az0 = __builtin_amdgcn_mfma_f32_16x16x32_bf16(wfrag[1][kc],     hv0, az0, 0, 0, 0);
        az1 = __builtin_amdgcn_mfma_f32_16x16x32_bf16(wfrag[1][kc + 8], hv1, az1, 0, 0, 0);
        an0 = __builtin_amdgcn_mfma_f32_16x16x32_bf16(wfrag[2][kc],     hv0, an0, 0, 0, 0);
        an1 = __builtin_amdgcn_mfma_f32_16x16x32_bf16(wfrag[2][kc + 8], hv1, an1, 0, 0, 0);
      }
      u64 xq0 = *(const u64*)(&xpq[par][cbase]);
      u64 xq1 = *(const u64*)(&xpq[par][64 + cbase]);
      u64 xq2 = *(const u64*)(&xpq[par][128 + cbase]);
      float hnew[4];
      #pragma unroll
      for (int r = 0; r < 4; ++r) {
        float xr = bf2f((ushort_t)(xq0 >> (r*16)));
        float xz = bf2f((ushort_t)(xq1 >> (r*16)));
        float xn = bf2f((ushort_t)(xq2 >> (r*16)));
        float hr = ar0[r] + ar1[r] + bhv[r];
        float hz = az0[r] + az1[r] + bhv[4 + r];
        float hn = an0[r] + an1[r] + bhv[8 + r];
        float rg = 1.0f/(1.0f + __expf(-(xr + hr)));
        float zg = 1.0f/(1.0f + __expf(-(xz + hz)));
        float ni = xn + rg*hn;
        float ng = 1.0f - 2.0f/(1.0f + __expf(2.0f*ni));   // tanh
        hnew[r] = (1.0f - zg)*ng + zg*hprev[r];
        hprev[r] = hnew[r];
      }
      if (l15 == 0) {
        int par2 = (t + 1) & 1;
        uint32 tag = (uint32)(t + 1) & 0xffffu;
        ushort_t b0 = f2bf(hnew[0]), b1 = f2bf(hnew[1]);
        ushort_t b2 = f2bf(hnew[2]), b3 = f2bf(hnew[3]);
        // FAST publish first (critical path), then own-LDS for next step
        u64 p0 = (((u64)((((uint32)b1) << 16) | tag)) << 32) | ((((uint32)b0) << 16) | tag);
        u64 p1 = (((u64)((((uint32)b3) << 16) | tag)) << 32) | ((((uint32)b2) << 16) | tag);
        store_u64_l2(hbF + par2*256 + (C0 >> 1),     p0);
        store_u64_l2(hbF + par2*256 + (C0 >> 1) + 1, p1);
        uint32 lo = ((uint32)b1 << 16) | b0;
        uint32 hi = ((uint32)b3 << 16) | b2;
        *(u64*)(&h_bf[par2][C0]) = (((u64)hi) << 32) | lo;
      }
    } else {
      if (xi < 48) {
        int tn = (t < 4095) ? (t + 1) : 4095;
        xreg = *(const u64*)(xpd + ((size_t)tn*1536 + (size_t)(xi >> 4)*512 + I0 + (xi & 15)*4));
      }
    }
  }
  // epilogue: outputs row for t=4095 (h(4095) lives at parity 0)
  if (wv == 4 && lane < 32) {
    uint32 want = 4096u & 0xffffu;
    const u64* aF = hbF + 0*256 + g*32 + lane;
    u64 v;
    for (;;) {
      v = load_u64_sc0(aF);
      if (((uint32)v & 0xffffu) == want &&
          (((uint32)(v >> 32)) & 0xffffu) == want) break;
    }
    int row = d ? 0 : 4095;
    float2 o;
    o.x = bf2f((ushort_t)(v >> 16));
    o.y = bf2f((ushort_t)(v >> 48));
    *(float2*)(outputs + (size_t)row*1024 + d*512 + I0 + lane*2) = o;
  }
  if (wv < 4 && l15 == 0) {
    float4 o; o.x = hprev[0]; o.y = hprev[1]; o.z = hprev[2]; o.w = hprev[3];
    *(float4*)(ws + WS_HID + (1 - d)*512 + C0) = o;
  }
}

// ============ K4a: scores[t] = outputs[t]·hid * scale  (+ zero lin) ============
__global__ __launch_bounds__(256) void k_scores(float* __restrict__ ws, float* __restrict__ outbase)
{
  if (blockIdx.x == 256) {
    float4 z = {0.f,0.f,0.f,0.f};
    ((float4*)outbase)[threadIdx.x] = z;
    return;
  }
  const float* outputs = outbase + ENERGY_OFF + OUTPUTS_OFF;
  const float* hid = ws + WS_HID;
  int tid = threadIdx.x, lane = tid & 63, wv = tid >> 6;
  float4 hv[4];
  #pragma unroll
  for (int c = 0; c < 4; ++c) hv[c] = *(const float4*)(hid + lane*16 + c*4);
  const float scale = 0.03125f;  // 1/sqrt(1024)
  for (int it = 0; it < 4; ++it) {
    int t = blockIdx.x*16 + wv*4 + it;
    const float4* o4 = (const float4*)(outputs + (size_t)t*1024 + lane*16);
    float p = 0.f;
    #pragma unroll
    for (int c = 0; c < 4; ++c) {
      float4 o = o4[c];
      p += o.x*hv[c].x + o.y*hv[c].y + o.z*hv[c].z + o.w*hv[c].w;
    }
    #pragma unroll
    for (int m = 1; m < 64; m <<= 1) p += __shfl_xor(p, m, 64);
    if (lane == 0) ws[WS_SCORES + t] = p*scale;
  }
}

// ============ K4b: softmax over 4096 scores (one block) ============
__global__ __launch_bounds__(1024) void k_softmax(float* __restrict__ ws)
{
  int tid = threadIdx.x, lane = tid & 63, wv = tid >> 6;
  __shared__ float sm[16];
  float4 s = *(const float4*)(ws + WS_SCORES + tid*4);
  float mx = fmaxf(fmaxf(s.x, s.y), fmaxf(s.z, s.w));
  #pragma unroll
  for (int m = 1; m < 64; m <<= 1) mx = fmaxf(mx, __shfl_xor(mx, m, 64));
  if (lane == 0) sm[wv] = mx;
  __syncthreads();
  float bm = sm[0];
  #pragma unroll
  for (int i = 1; i < 16; ++i) bm = fmaxf(bm, sm[i]);
  float e0 = __expf(s.x - bm), e1 = __expf(s.y - bm);
  float e2 = __expf(s.z - bm), e3 = __expf(s.w - bm);
  float ps = e0 + e1 + e2 + e3;
  #pragma unroll
  for (int m = 1; m < 64; m <<= 1) ps += __shfl_xor(ps, m, 64);
  __syncthreads();
  if (lane == 0) sm[wv] = ps;
  __syncthreads();
  float tot = 0.f;
  #pragma unroll
  for (int i = 0; i < 16; ++i) tot += sm[i];
  float inv = 1.0f/tot;
  float4 a = {e0*inv, e1*inv, e2*inv, e3*inv};
  *(float4*)(ws + WS_ATT + tid*4) = a;
}

// ============ K4c: lin[j] = sum_t att[t]*outputs[t][j] ============
__global__ __launch_bounds__(256) void k_lin(const float* __restrict__ ws, float* __restrict__ outbase)
{
  const float* outputs = outbase + ENERGY_OFF + OUTPUTS_OFF;
  const float* att = ws + WS_ATT;
  int jb = blockIdx.x & 3, tseg = blockIdx.x >> 2;
  int j = jb*256 + threadIdx.x;
  float acc = 0.f;
  int t0 = tseg*256;
  for (int t = t0; t < t0 + 256; ++t)
    acc += att[t]*outputs[(size_t)t*1024 + j];
  atomicAdd(outbase + j, acc);
}

// ============ K5: energy = diag(e), overwrites the whole scratch region ============
__global__ __launch_bounds__(256) void k_energy(const float* __restrict__ ws, float* __restrict__ outbase)
{
  float* energy = outbase + ENERGY_OFF;
  int t = blockIdx.x;
  float e = ws[WS_E + t];
  #pragma unroll
  for (int k = 0; k < 4; ++k) {
    int c4 = (threadIdx.x + k*256)*4;
    float4 v = {0.f,0.f,0.f,0.f};
    if (t >= c4 && t < c4 + 4) ((float*)&v)[t - c4] = e;
    *(float4*)(energy + (size_t)t*4096 + c4) = v;
  }
}

extern "C" void kernel_launch(void* const* d_in, const int* in_sizes, int n_in,
                              void* d_out, int out_size, void* d_ws, size_t ws_size,
                              hipStream_t stream) {
  const float* input  = (const float*)d_in[0];
  const float* query  = (const float*)d_in[1];
  const float* fc_w   = (const float*)d_in[2];
  const float* fc_b   = (const float*)d_in[3];
  const float* w_ih_f = (const float*)d_in[4];
  const float* w_hh_f = (const float*)d_in[5];
  const float* b_ih_f = (const float*)d_in[6];
  const float* b_hh_f = (const float*)d_in[7];
  const float* w_ih_b = (const float*)d_in[8];
  const float* w_hh_b = (const float*)d_in[9];
  const float* b_ih_b = (const float*)d_in[10];
  const float* b_hh_b = (const float*)d_in[11];
  float* out = (float*)d_out;
  float* ws  = (float*)d_ws;

  hipLaunchKernelGGL(k_prep,    dim3(2048),   dim3(256),  0, stream,
                     query, input, fc_w, fc_b, w_ih_f, w_ih_b, w_hh_f, w_hh_b, ws, out);
  hipLaunchKernelGGL(k_xp_gemm, dim3(64, 48), dim3(256),  0, stream, b_ih_f, b_ih_b, out);
  hipLaunchKernelGGL(k_gru,     dim3(64),     dim3(320),  0, stream, b_hh_f, b_hh_b, ws, out);
  hipLaunchKernelGGL(k_scores,  dim3(257),    dim3(256),  0, stream, ws, out);
  hipLaunchKernelGGL(k_softmax, dim3(1),      dim3(1024), 0, stream, ws);
  hipLaunchKernelGGL(k_lin,     dim3(64),     dim3(256),  0, stream, ws, out);
  hipLaunchKernelGGL(k_energy,  dim3(4096),   dim3(256),  0, stream, ws, out);
}

// Round 5
// 6035.120 us; speedup vs baseline: 2.0793x; 2.0793x over previous
//
#include <hip/hip_runtime.h>
#include <math.h>

typedef __attribute__((ext_vector_type(8))) short short8;
typedef __attribute__((ext_vector_type(4))) float f32x4;
typedef unsigned short ushort_t;
typedef unsigned int uint32;
typedef unsigned long long u64;

// ---------------- ws layout (float units) ----------------
#define WS_E      0        // e[4096]
#define WS_SCORES 4096     // scores[4096]
#define WS_ATT    8192     // att[4096]
#define WS_HID    12288    // hid[1024]
#define WS_HBUF   16384    // u64 hbuf[2 dir][2 parity][256]  (8 KB)

// ---------------- d_out layout (float units from base) ----------------
#define ENERGY_OFF   1024
#define XP_OFF       0          // bf16 xp[2][4096][1536]
#define OUTPUTS_OFF  6291456    // float outputs[4096][1024]
#define XBF_OFF      10485760   // bf16 x[4096][512]
#define WIH_OFF      11534336   // bf16 w_ih[3072][512]
#define WHH_OFF      12320768   // bf16 w_hh[2][1536][512]

__device__ __forceinline__ ushort_t f2bf(float f) {
  uint32 x = __float_as_uint(f);
  return (ushort_t)((x + 0x7fffu + ((x >> 16) & 1u)) >> 16);
}
__device__ __forceinline__ float bf2f(ushort_t u) {
  return __uint_as_float(((uint32)u) << 16);
}

// ============ K1: e[t], x_bf, weight bf16 conversion ============
__global__ __launch_bounds__(256) void k_prep(
    const float* __restrict__ query, const float* __restrict__ input,
    const float* __restrict__ fc_w, const float* __restrict__ fc_b,
    const float* __restrict__ w_ih_f, const float* __restrict__ w_ih_b,
    const float* __restrict__ w_hh_f, const float* __restrict__ w_hh_b,
    float* __restrict__ ws, float* __restrict__ outbase)
{
  int bid = blockIdx.x, tid = threadIdx.x;
  ushort_t* xbf   = (ushort_t*)(outbase + ENERGY_OFF + XBF_OFF);
  ushort_t* wihbf = (ushort_t*)(outbase + ENERGY_OFF + WIH_OFF);
  ushort_t* whhbf = (ushort_t*)(outbase + ENERGY_OFF + WHH_OFF);

  if (bid < 512) {
    int lane = tid & 63, wv = tid >> 6;
    float bconst = fc_b[0];
    const float4* w4 = (const float4*)fc_w;
    float4 b0 = w4[lane*2], b1 = w4[lane*2+1];
    for (int it = 0; it < 2; ++it) {
      int t = bid*8 + it*4 + wv;
      const float4* q4 = (const float4*)(query + (size_t)t*512);
      float4 a0 = q4[lane*2], a1 = q4[lane*2+1];
      float p = a0.x*b0.x + a0.y*b0.y + a0.z*b0.z + a0.w*b0.w
              + a1.x*b1.x + a1.y*b1.y + a1.z*b1.z + a1.w*b1.w;
      #pragma unroll
      for (int m = 1; m < 64; m <<= 1) p += __shfl_xor(p, m, 64);
      float e = p + bconst;
      if (lane == 0) ws[WS_E + t] = e;
      const float4* in4 = (const float4*)(input + (size_t)t*512);
      float4 x0 = in4[lane*2], x1 = in4[lane*2+1];
      short8 o;
      o[0]=(short)f2bf(e*x0.x); o[1]=(short)f2bf(e*x0.y);
      o[2]=(short)f2bf(e*x0.z); o[3]=(short)f2bf(e*x0.w);
      o[4]=(short)f2bf(e*x1.x); o[5]=(short)f2bf(e*x1.y);
      o[6]=(short)f2bf(e*x1.z); o[7]=(short)f2bf(e*x1.w);
      *(short8*)(xbf + (size_t)t*512 + lane*8) = o;
    }
  } else {
    size_t gid = (size_t)(bid - 512)*2048 + (size_t)tid*8;
    const float* src; ushort_t* dst; size_t doff, soff;
    if (gid < 786432)        { src = w_ih_f; dst = wihbf; doff = gid;          soff = gid; }
    else if (gid < 1572864)  { src = w_ih_b; dst = wihbf; doff = gid;          soff = gid - 786432; }
    else if (gid < 2359296)  { src = w_hh_f; dst = whhbf; doff = gid - 1572864; soff = gid - 1572864; }
    else                     { src = w_hh_b; dst = whhbf; doff = gid - 1572864; soff = gid - 2359296; }
    float4 v0 = *(const float4*)(src + soff);
    float4 v1 = *(const float4*)(src + soff + 4);
    short8 o;
    o[0]=(short)f2bf(v0.x); o[1]=(short)f2bf(v0.y); o[2]=(short)f2bf(v0.z); o[3]=(short)f2bf(v0.w);
    o[4]=(short)f2bf(v1.x); o[5]=(short)f2bf(v1.y); o[6]=(short)f2bf(v1.z); o[7]=(short)f2bf(v1.w);
    *(short8*)(dst + doff) = o;
  }
}

// ============ K2: xp GEMM  (folds b_ih for all gates + b_hh for r,z) ============
__global__ __launch_bounds__(256) void k_xp_gemm(
    const float* __restrict__ b_ih_f, const float* __restrict__ b_ih_b,
    const float* __restrict__ b_hh_f, const float* __restrict__ b_hh_b,
    float* __restrict__ outbase)
{
  const ushort_t* xbf   = (const ushort_t*)(outbase + ENERGY_OFF + XBF_OFF);
  const ushort_t* wihbf = (const ushort_t*)(outbase + ENERGY_OFF + WIH_OFF);
  ushort_t* xpbf = (ushort_t*)(outbase + ENERGY_OFF + XP_OFF);

  int m0 = blockIdx.x * 64, n0 = blockIdx.y * 64;
  bool rev = (n0 >= 1536);
  __shared__ ushort_t As[64*40];
  __shared__ ushort_t Bs[64*40];
  int tid = threadIdx.x;
  int lane = tid & 63, wv = tid >> 6, l15 = lane & 15, quad = lane >> 4;
  int mw = (wv & 1)*32, nw = (wv >> 1)*32;
  f32x4 acc[2][2] = {};
  int lr = tid >> 2, lc = (tid & 3)*8;
  int t_eff = rev ? (4095 - (m0 + lr)) : (m0 + lr);
  const short8* asrc = (const short8*)(xbf + (size_t)t_eff*512 + lc);
  const short8* bsrc = (const short8*)(wihbf + (size_t)(n0 + lr)*512 + lc);

  for (int ks = 0; ks < 16; ++ks) {
    short8 av = asrc[ks*4];
    short8 bv = bsrc[ks*4];
    __syncthreads();
    *(short8*)(As + lr*40 + lc) = av;
    *(short8*)(Bs + lr*40 + lc) = bv;
    __syncthreads();
    short8 bf0 = *(const short8*)(Bs + (nw + l15)*40 + quad*8);
    short8 bf1 = *(const short8*)(Bs + (nw + 16 + l15)*40 + quad*8);
    #pragma unroll
    for (int mi = 0; mi < 2; ++mi) {
      short8 af = *(const short8*)(As + (mw + mi*16 + l15)*40 + quad*8);
      acc[mi][0] = __builtin_amdgcn_mfma_f32_16x16x32_bf16(af, bf0, acc[mi][0], 0, 0, 0);
      acc[mi][1] = __builtin_amdgcn_mfma_f32_16x16x32_bf16(af, bf1, acc[mi][1], 0, 0, 0);
    }
  }
  #pragma unroll
  for (int mi = 0; mi < 2; ++mi) {
    #pragma unroll
    for (int ni = 0; ni < 2; ++ni) {
      int j = n0 + nw + ni*16 + l15;
      int d2 = (j >= 1536) ? 1 : 0;
      int jj = j - d2*1536;
      bool is_n = (jj >= 1024);        // gate n: b_hh must stay inside r*(...)
      float bias = d2 ? (b_ih_b[jj] + (is_n ? 0.f : b_hh_b[jj]))
                      : (b_ih_f[jj] + (is_n ? 0.f : b_hh_f[jj]));
      int trow_base = m0 + mw + mi*16 + quad*4;
      #pragma unroll
      for (int r = 0; r < 4; ++r) {
        xpbf[((size_t)(d2*4096 + trow_base + r))*1536 + jj] = f2bf(acc[mi][ni][r] + bias);
      }
    }
  }
}

// ============ K3: persistent bidirectional GRU scan ============
// 64 WGs (blk>>5 = dir, blk&31 = g), 16 ch/WG, 320 threads.
//   waves 0..3: poll foreign h-words -> LDS, K-split MFMA (12 frags VGPR-resident)
//   wave 0 lanes<16: gates + tagged agent-scope publish (R1-proven exchange)
//   wave 4: xp streaming + outputs rows (keeps stores off the polling waves)
// Two barriers/step: P1(poll,xp-commit) | P2(MFMA->partials, outputs) | P3(gates).
__global__ __launch_bounds__(320, 1) void k_gru(
    const float* __restrict__ b_hh_f, const float* __restrict__ b_hh_b,
    float* __restrict__ ws, float* __restrict__ outbase)
{
  const ushort_t* xpbf  = (const ushort_t*)(outbase + ENERGY_OFF + XP_OFF);
  const ushort_t* whhbf = (const ushort_t*)(outbase + ENERGY_OFF + WHH_OFF);
  float* outputs = outbase + ENERGY_OFF + OUTPUTS_OFF;

  int blk = blockIdx.x;
  int d = blk >> 5, g = blk & 31;
  int tid = threadIdx.x;
  int lane = tid & 63, wv = tid >> 6, l15 = lane & 15, quad = lane >> 4;
  int I0 = g * 16;

  u64* hb = ((u64*)(ws + WS_HBUF)) + d * 512;          // [parity][256]
  const ushort_t* xpd = xpbf + (size_t)d * 4096 * 1536;

  __shared__ uint32 hlds[2][256];                       // h bf16 pairs per parity
  __shared__ float part[192] __attribute__((aligned(16)));
  __shared__ ushort_t xpq[2][48];

  // W_hh fragments, K-split: wave w covers k in [w*128,(w+1)*128). Loaded
  // UNCONDITIONALLY (wave 4 aliases wave 0's) so the compiler cannot sink the
  // loads into the loop (R1's VGPR_Count=52 proved it did exactly that).
  int wk = wv & 3;
  short8 wfrag[12];
  {
    const ushort_t* wbase = whhbf + (size_t)d * 1536 * 512;
    #pragma unroll
    for (int g3 = 0; g3 < 3; ++g3) {
      #pragma unroll
      for (int kc = 0; kc < 4; ++kc)
        wfrag[g3*4 + kc] = *(const short8*)(wbase
            + ((size_t)(g3*512 + I0 + l15))*512 + wk*128 + kc*32 + quad*8);
    }
  }
  float bhn_c = 0.f;
  if (wv == 0 && lane < 16) bhn_c = (d ? b_hh_b : b_hh_f)[1024 + I0 + lane];
  if (wv < 4) hlds[0][tid] = 0;
  ushort_t xreg = 0;
  if (wv == 4 && lane < 48)
    xreg = xpd[(size_t)(lane >> 4)*512 + I0 + (lane & 15)];
  float hprev = 0.f;
  __syncthreads();

  for (int t = 0; t < 4096; ++t) {
    int par = t & 1;
    // ---- P1: poll foreign words (tag-validated) / commit xp[t] ----
    if (wv < 4) {
      if (t > 0 && (tid >> 3) != g) {
        uint32 want = (uint32)t;                 // publisher tag for h(t-1) is t
        const u64* a = hb + par*256 + tid;
        u64 v = __hip_atomic_load(a, __ATOMIC_RELAXED, __HIP_MEMORY_SCOPE_AGENT);
        while (((uint32)v & 0xffffu) != want ||
               ((uint32)(v >> 32) & 0xffffu) != want) {
          __builtin_amdgcn_s_sleep(1);
          v = __hip_atomic_load(a, __ATOMIC_RELAXED, __HIP_MEMORY_SCOPE_AGENT);
        }
        hlds[par][tid] = (uint32)(((v >> 16) & 0xffffu) | ((v >> 32) & 0xffff0000u));
      }
    } else {
      if (lane < 48) xpq[par][lane] = xreg;
    }
    __syncthreads();
    // ---- P2: K-split matvec -> partials / outputs row t-1 + xp prefetch ----
    if (wv < 4) {
      f32x4 a0 = {0.f,0.f,0.f,0.f}, a1 = {0.f,0.f,0.f,0.f}, a2 = {0.f,0.f,0.f,0.f};
      const ushort_t* hq = ((const ushort_t*)&hlds[par][0]) + wv*128;
      #pragma unroll
      for (int kc = 0; kc < 4; ++kc) {
        short8 hv = *(const short8*)(hq + kc*32 + quad*8);
        a0 = __builtin_amdgcn_mfma_f32_16x16x32_bf16(wfrag[kc],     hv, a0, 0, 0, 0);
        a1 = __builtin_amdgcn_mfma_f32_16x16x32_bf16(wfrag[4 + kc], hv, a1, 0, 0, 0);
        a2 = __builtin_amdgcn_mfma_f32_16x16x32_bf16(wfrag[8 + kc], hv, a2, 0, 0, 0);
      }
      if (l15 == 0) {
        *(f32x4*)&part[wv*48 + quad*4]      = a0;
        *(f32x4*)&part[wv*48 + 16 + quad*4] = a1;
        *(f32x4*)&part[wv*48 + 32 + quad*4] = a2;
      }
    } else {
      if (t > 0 && lane < 8) {
        uint32 w = hlds[par][g*8 + lane];        // own pair, written step t-1 P3
        int row = d ? (4095 - (t - 1)) : (t - 1);
        float2 o;
        o.x = bf2f((ushort_t)(w & 0xffffu));
        o.y = bf2f((ushort_t)(w >> 16));
        *(float2*)(outputs + (size_t)row*1024 + d*512 + I0 + lane*2) = o;
      }
      if (lane < 48) {
        int tn = (t < 4095) ? (t + 1) : 4095;
        xreg = xpd[(size_t)tn*1536 + (size_t)(lane >> 4)*512 + I0 + (lane & 15)];
      }
    }
    __syncthreads();
    // ---- P3: gates + publish (wave 0, lanes 0..15; one channel per lane) ----
    if (wv == 0 && lane < 16) {
      int c = lane;
      float hr = part[c]      + part[48 + c] + part[96 + c]  + part[144 + c];
      float hz = part[16 + c] + part[64 + c] + part[112 + c] + part[160 + c];
      float hn = part[32 + c] + part[80 + c] + part[128 + c] + part[176 + c];
      float xr = bf2f(xpq[par][c]);            // b_ih + b_hh folded (r)
      float xz = bf2f(xpq[par][16 + c]);       // b_ih + b_hh folded (z)
      float xn = bf2f(xpq[par][32 + c]);       // b_ih only (n)
      float rg = 1.0f/(1.0f + __expf(-(xr + hr)));
      float zg = 1.0f/(1.0f + __expf(-(xz + hz)));
      float ni = xn + rg*(hn + bhn_c);
      float ng = 1.0f - 2.0f/(1.0f + __expf(2.0f*ni));   // tanh
      float h = (1.0f - zg)*ng + zg*hprev;
      hprev = h;
      int par2 = (t + 1) & 1;
      uint32 tag = (uint32)(t + 1) & 0xffffu;
      uint32 myd = (((uint32)f2bf(h)) << 16) | tag;
      uint32 pd = (uint32)__shfl_xor((int)myd, 1, 64);
      if ((c & 1) == 0) {
        u64 w = (((u64)pd) << 32) | (u64)myd;  // lo: ch even, hi: ch odd
        __hip_atomic_store(hb + par2*256 + g*8 + (c >> 1), w,
                           __ATOMIC_RELAXED, __HIP_MEMORY_SCOPE_AGENT);
        hlds[par2][g*8 + (c >> 1)] = (myd >> 16) | (pd & 0xffff0000u);
      }
    }
    // no barrier here: P3 writes only hlds[par2]; next P1 writes disjoint
    // foreign words of hlds[par2]; next P2's reads are behind next P1's barrier.
  }
  if (wv == 0 && lane < 16) {
    int row = d ? 0 : 4095;                     // last produced output row
    outputs[(size_t)row*1024 + d*512 + I0 + lane] = hprev;
    ws[WS_HID + (1 - d)*512 + I0 + lane] = hprev;
  }
}

// ============ K4a: scores[t] = outputs[t]·hid * scale  (+ zero lin) ============
__global__ __launch_bounds__(256) void k_scores(float* __restrict__ ws, float* __restrict__ outbase)
{
  if (blockIdx.x == 256) {
    float4 z = {0.f,0.f,0.f,0.f};
    ((float4*)outbase)[threadIdx.x] = z;
    return;
  }
  const float* outputs = outbase + ENERGY_OFF + OUTPUTS_OFF;
  const float* hid = ws + WS_HID;
  int tid = threadIdx.x, lane = tid & 63, wv = tid >> 6;
  float4 hv[4];
  #pragma unroll
  for (int c = 0; c < 4; ++c) hv[c] = *(const float4*)(hid + lane*16 + c*4);
  const float scale = 0.03125f;  // 1/sqrt(1024)
  for (int it = 0; it < 4; ++it) {
    int t = blockIdx.x*16 + wv*4 + it;
    const float4* o4 = (const float4*)(outputs + (size_t)t*1024 + lane*16);
    float p = 0.f;
    #pragma unroll
    for (int c = 0; c < 4; ++c) {
      float4 o = o4[c];
      p += o.x*hv[c].x + o.y*hv[c].y + o.z*hv[c].z + o.w*hv[c].w;
    }
    #pragma unroll
    for (int m = 1; m < 64; m <<= 1) p += __shfl_xor(p, m, 64);
    if (lane == 0) ws[WS_SCORES + t] = p*scale;
  }
}

// ============ K4b: softmax over 4096 scores (one block) ============
__global__ __launch_bounds__(1024) void k_softmax(float* __restrict__ ws)
{
  int tid = threadIdx.x, lane = tid & 63, wv = tid >> 6;
  __shared__ float sm[16];
  float4 s = *(const float4*)(ws + WS_SCORES + tid*4);
  float mx = fmaxf(fmaxf(s.x, s.y), fmaxf(s.z, s.w));
  #pragma unroll
  for (int m = 1; m < 64; m <<= 1) mx = fmaxf(mx, __shfl_xor(mx, m, 64));
  if (lane == 0) sm[wv] = mx;
  __syncthreads();
  float bm = sm[0];
  #pragma unroll
  for (int i = 1; i < 16; ++i) bm = fmaxf(bm, sm[i]);
  float e0 = __expf(s.x - bm), e1 = __expf(s.y - bm);
  float e2 = __expf(s.z - bm), e3 = __expf(s.w - bm);
  float ps = e0 + e1 + e2 + e3;
  #pragma unroll
  for (int m = 1; m < 64; m <<= 1) ps += __shfl_xor(ps, m, 64);
  __syncthreads();
  if (lane == 0) sm[wv] = ps;
  __syncthreads();
  float tot = 0.f;
  #pragma unroll
  for (int i = 0; i < 16; ++i) tot += sm[i];
  float inv = 1.0f/tot;
  float4 a = {e0*inv, e1*inv, e2*inv, e3*inv};
  *(float4*)(ws + WS_ATT + tid*4) = a;
}

// ============ K4c: lin[j] = sum_t att[t]*outputs[t][j] ============
__global__ __launch_bounds__(256) void k_lin(const float* __restrict__ ws, float* __restrict__ outbase)
{
  const float* outputs = outbase + ENERGY_OFF + OUTPUTS_OFF;
  const float* att = ws + WS_ATT;
  int jb = blockIdx.x & 3, tseg = blockIdx.x >> 2;
  int j = jb*256 + threadIdx.x;
  float acc = 0.f;
  int t0 = tseg*256;
  for (int t = t0; t < t0 + 256; ++t)
    acc += att[t]*outputs[(size_t)t*1024 + j];
  atomicAdd(outbase + j, acc);
}

// ============ K5: energy = diag(e), overwrites the whole scratch region ============
__global__ __launch_bounds__(256) void k_energy(const float* __restrict__ ws, float* __restrict__ outbase)
{
  float* energy = outbase + ENERGY_OFF;
  int t = blockIdx.x;
  float e = ws[WS_E + t];
  #pragma unroll
  for (int k = 0; k < 4; ++k) {
    int c4 = (threadIdx.x + k*256)*4;
    float4 v = {0.f,0.f,0.f,0.f};
    if (t >= c4 && t < c4 + 4) ((float*)&v)[t - c4] = e;
    *(float4*)(energy + (size_t)t*4096 + c4) = v;
  }
}

extern "C" void kernel_launch(void* const* d_in, const int* in_sizes, int n_in,
                              void* d_out, int out_size, void* d_ws, size_t ws_size,
                              hipStream_t stream) {
  const float* input  = (const float*)d_in[0];
  const float* query  = (const float*)d_in[1];
  const float* fc_w   = (const float*)d_in[2];
  const float* fc_b   = (const float*)d_in[3];
  const float* w_ih_f = (const float*)d_in[4];
  const float* w_hh_f = (const float*)d_in[5];
  const float* b_ih_f = (const float*)d_in[6];
  const float* b_hh_f = (const float*)d_in[7];
  const float* w_ih_b = (const float*)d_in[8];
  const float* w_hh_b = (const float*)d_in[9];
  const float* b_ih_b = (const float*)d_in[10];
  const float* b_hh_b = (const float*)d_in[11];
  float* out = (float*)d_out;
  float* ws  = (float*)d_ws;

  hipLaunchKernelGGL(k_prep,    dim3(2048),   dim3(256),  0, stream,
                     query, input, fc_w, fc_b, w_ih_f, w_ih_b, w_hh_f, w_hh_b, ws, out);
  hipLaunchKernelGGL(k_xp_gemm, dim3(64, 48), dim3(256),  0, stream,
                     b_ih_f, b_ih_b, b_hh_f, b_hh_b, out);
  hipLaunchKernelGGL(k_gru,     dim3(64),     dim3(320),  0, stream, b_hh_f, b_hh_b, ws, out);
  hipLaunchKernelGGL(k_scores,  dim3(257),    dim3(256),  0, stream, ws, out);
  hipLaunchKernelGGL(k_softmax, dim3(1),      dim3(1024), 0, stream, ws);
  hipLaunchKernelGGL(k_lin,     dim3(64),     dim3(256),  0, stream, ws, out);
  hipLaunchKernelGGL(k_energy,  dim3(4096),   dim3(256),  0, stream, ws, out);
}